// Round 1
// baseline (2905.545 us; speedup 1.0000x reference)
//
#include <hip/hip_runtime.h>

#define N_NODES 100000
#define N_EDGES 1600000
#define DIM 128

// ---------------------------------------------------------------------------
// Phase 1: per-edge message + scatter-add (atomics baseline)
// 32 lanes per edge, each lane owns a float4 chunk (32*4 = 128 dims).
// ---------------------------------------------------------------------------
__global__ __launch_bounds__(256) void gine_scatter(
    const float* __restrict__ x,
    const int* __restrict__ ei,     // [2, E] row-major: src then dst
    const int* __restrict__ ea,     // [E]
    const float* __restrict__ emb,  // [4, 128]
    float* __restrict__ agg)        // [N, 128] pre-zeroed
{
    int gid = blockIdx.x * blockDim.x + threadIdx.x;
    int e = gid >> 5;
    if (e >= N_EDGES) return;
    int c = gid & 31;

    int src = ei[e];
    int dst = ei[N_EDGES + e];
    int at  = ea[e];

    float4 xv = ((const float4*)(x + (size_t)src * DIM))[c];
    float4 ev = ((const float4*)(emb + (size_t)at * DIM))[c];
    float4 m;
    m.x = fmaxf(xv.x + ev.x, 0.0f);
    m.y = fmaxf(xv.y + ev.y, 0.0f);
    m.z = fmaxf(xv.z + ev.z, 0.0f);
    m.w = fmaxf(xv.w + ev.w, 0.0f);

    float* o = agg + (size_t)dst * DIM + c * 4;
    atomicAdd(o + 0, m.x);
    atomicAdd(o + 1, m.y);
    atomicAdd(o + 2, m.z);
    atomicAdd(o + 3, m.w);
}

// ---------------------------------------------------------------------------
// Phase 2a: h = (1+eps)*x + agg ; h1 = LN(h@W1 + b1) ; relu ; write back into
// agg rows (block-exclusive rows -> safe in-place).
// Block: 256 threads = 8 nodes x 32 lanes; lane owns 4 output dims.
// W1 staged in LDS (64KB).
// ---------------------------------------------------------------------------
__global__ __launch_bounds__(256) void gine_mlp1(
    const float* __restrict__ x,
    const float* __restrict__ eps_p,
    const float* __restrict__ W1,
    const float* __restrict__ b1,
    const float* __restrict__ ln_g,
    const float* __restrict__ ln_b,
    float* __restrict__ agg)
{
    __shared__ float w1s[DIM * DIM];   // 64KB
    __shared__ float hrow[8][DIM];     // 4KB

    for (int i = threadIdx.x; i < DIM * DIM / 4; i += 256)
        ((float4*)w1s)[i] = ((const float4*)W1)[i];

    const float epsv = 1.0f + eps_p[0];
    const int n_local = threadIdx.x >> 5;   // 0..7
    const int lane32  = threadIdx.x & 31;
    const int jj = lane32 * 4;

    const float4 bv = *(const float4*)(b1 + jj);
    const float4 gv = *(const float4*)(ln_g + jj);
    const float4 bb = *(const float4*)(ln_b + jj);

    for (int base = blockIdx.x * 8; base < N_NODES; base += gridDim.x * 8) {
        __syncthreads();   // protect hrow reuse across iterations
        {
            int r = threadIdx.x >> 5, c = threadIdx.x & 31;
            int node = base + r;
            if (node < N_NODES) {
                float4 xv = ((const float4*)(x   + (size_t)node * DIM))[c];
                float4 av = ((const float4*)(agg + (size_t)node * DIM))[c];
                float4 h;
                h.x = epsv * xv.x + av.x;
                h.y = epsv * xv.y + av.y;
                h.z = epsv * xv.z + av.z;
                h.w = epsv * xv.w + av.w;
                ((float4*)hrow[r])[c] = h;
            }
        }
        __syncthreads();

        int node = base + n_local;
        if (node >= N_NODES) continue;

        float4 acc = bv;
        #pragma unroll 8
        for (int k = 0; k < DIM; ++k) {
            float hv = hrow[n_local][k];
            float4 wv = *(const float4*)(w1s + k * DIM + jj);
            acc.x = fmaf(hv, wv.x, acc.x);
            acc.y = fmaf(hv, wv.y, acc.y);
            acc.z = fmaf(hv, wv.z, acc.z);
            acc.w = fmaf(hv, wv.w, acc.w);
        }

        // LayerNorm over 128 outputs: reduce across this node's 32 lanes
        float s1 = acc.x + acc.y + acc.z + acc.w;
        float s2 = acc.x * acc.x + acc.y * acc.y + acc.z * acc.z + acc.w * acc.w;
        #pragma unroll
        for (int m = 16; m; m >>= 1) {
            s1 += __shfl_xor(s1, m);
            s2 += __shfl_xor(s2, m);
        }
        float mu  = s1 * (1.0f / DIM);
        float var = s2 * (1.0f / DIM) - mu * mu;
        float rs  = rsqrtf(var + 1e-5f);

        float4 o;
        o.x = fmaxf((acc.x - mu) * rs * gv.x + bb.x, 0.0f);
        o.y = fmaxf((acc.y - mu) * rs * gv.y + bb.y, 0.0f);
        o.z = fmaxf((acc.z - mu) * rs * gv.z + bb.z, 0.0f);
        o.w = fmaxf((acc.w - mu) * rs * gv.w + bb.w, 0.0f);
        *(float4*)(agg + (size_t)node * DIM + jj) = o;
    }
}

// ---------------------------------------------------------------------------
// Phase 2b: out = h1 @ W2 + b2
// ---------------------------------------------------------------------------
__global__ __launch_bounds__(256) void gine_mlp2(
    const float* __restrict__ h1,
    const float* __restrict__ W2,
    const float* __restrict__ b2,
    float* __restrict__ out)
{
    __shared__ float w2s[DIM * DIM];
    __shared__ float hrow[8][DIM];

    for (int i = threadIdx.x; i < DIM * DIM / 4; i += 256)
        ((float4*)w2s)[i] = ((const float4*)W2)[i];

    const int n_local = threadIdx.x >> 5;
    const int lane32  = threadIdx.x & 31;
    const int jj = lane32 * 4;
    const float4 bv = *(const float4*)(b2 + jj);

    for (int base = blockIdx.x * 8; base < N_NODES; base += gridDim.x * 8) {
        __syncthreads();
        {
            int r = threadIdx.x >> 5, c = threadIdx.x & 31;
            int node = base + r;
            if (node < N_NODES)
                ((float4*)hrow[r])[c] = ((const float4*)(h1 + (size_t)node * DIM))[c];
        }
        __syncthreads();

        int node = base + n_local;
        if (node >= N_NODES) continue;

        float4 acc = bv;
        #pragma unroll 8
        for (int k = 0; k < DIM; ++k) {
            float hv = hrow[n_local][k];
            float4 wv = *(const float4*)(w2s + k * DIM + jj);
            acc.x = fmaf(hv, wv.x, acc.x);
            acc.y = fmaf(hv, wv.y, acc.y);
            acc.z = fmaf(hv, wv.z, acc.z);
            acc.w = fmaf(hv, wv.w, acc.w);
        }
        *(float4*)(out + (size_t)node * DIM + jj) = acc;
    }
}

extern "C" void kernel_launch(void* const* d_in, const int* in_sizes, int n_in,
                              void* d_out, int out_size, void* d_ws, size_t ws_size,
                              hipStream_t stream) {
    const float* x    = (const float*)d_in[0];
    const int*   ei   = (const int*)d_in[1];
    const int*   ea   = (const int*)d_in[2];
    const float* emb  = (const float*)d_in[3];
    const float* epsp = (const float*)d_in[4];
    const float* W1   = (const float*)d_in[5];
    const float* b1   = (const float*)d_in[6];
    const float* lng  = (const float*)d_in[7];
    const float* lnb  = (const float*)d_in[8];
    const float* W2   = (const float*)d_in[9];
    const float* b2   = (const float*)d_in[10];
    float* out = (float*)d_out;
    float* agg = (float*)d_ws;   // [N_NODES, DIM] f32 = 51.2 MB

    hipMemsetAsync(d_ws, 0, (size_t)N_NODES * DIM * sizeof(float), stream);

    int scatter_threads = N_EDGES * 32;
    int scatter_blocks = (scatter_threads + 255) / 256;   // 200000
    gine_scatter<<<scatter_blocks, 256, 0, stream>>>(x, ei, ea, emb, agg);

    gine_mlp1<<<512, 256, 0, stream>>>(x, epsp, W1, b1, lng, lnb, agg);
    gine_mlp2<<<512, 256, 0, stream>>>(agg, W2, b2, out);
}

// Round 2
// 591.469 us; speedup vs baseline: 4.9124x; 4.9124x over previous
//
#include <hip/hip_runtime.h>

#define N_NODES 100000
#define N_EDGES 1600000
#define DIM 128
#define NB 98   // ceil(N_NODES / 1024)

// ---------------------------------------------------------------------------
// CSR build: histogram -> block scan -> scan of block sums -> add offsets -> fill
// ---------------------------------------------------------------------------
__global__ __launch_bounds__(256) void hist_kernel(
    const int* __restrict__ ei, int* __restrict__ cur)
{
    int e = blockIdx.x * 256 + threadIdx.x;
    if (e < N_EDGES) atomicAdd(&cur[ei[N_EDGES + e]], 1);
}

__global__ __launch_bounds__(256) void scan1_kernel(
    const int* __restrict__ deg, int* __restrict__ rs, int* __restrict__ bsums)
{
    __shared__ int s[256];
    int t = threadIdx.x;
    int base = blockIdx.x * 1024 + t * 4;
    int v0 = (base + 0 < N_NODES) ? deg[base + 0] : 0;
    int v1 = (base + 1 < N_NODES) ? deg[base + 1] : 0;
    int v2 = (base + 2 < N_NODES) ? deg[base + 2] : 0;
    int v3 = (base + 3 < N_NODES) ? deg[base + 3] : 0;
    int sum = v0 + v1 + v2 + v3;
    s[t] = sum;
    __syncthreads();
    for (int off = 1; off < 256; off <<= 1) {
        int x = (t >= off) ? s[t - off] : 0;
        __syncthreads();
        s[t] += x;
        __syncthreads();
    }
    int excl = s[t] - sum;
    if (base + 0 < N_NODES) rs[base + 0] = excl;  excl += v0;
    if (base + 1 < N_NODES) rs[base + 1] = excl;  excl += v1;
    if (base + 2 < N_NODES) rs[base + 2] = excl;  excl += v2;
    if (base + 3 < N_NODES) rs[base + 3] = excl;
    if (t == 255) bsums[blockIdx.x] = s[255];
}

__global__ __launch_bounds__(128) void scan2_kernel(int* __restrict__ bsums)
{
    __shared__ int s[128];
    int t = threadIdx.x;
    int v = (t < NB) ? bsums[t] : 0;
    s[t] = v;
    __syncthreads();
    for (int off = 1; off < 128; off <<= 1) {
        int x = (t >= off) ? s[t - off] : 0;
        __syncthreads();
        s[t] += x;
        __syncthreads();
    }
    if (t < NB) bsums[t] = s[t] - v;   // exclusive
}

__global__ __launch_bounds__(256) void scan3_kernel(
    int* __restrict__ rs, int* __restrict__ cur, const int* __restrict__ bsums)
{
    int i = blockIdx.x * 256 + threadIdx.x;
    if (i < N_NODES) {
        int v = rs[i] + bsums[i >> 10];
        rs[i] = v;
        cur[i] = v;
    }
    if (i == 0) rs[N_NODES] = N_EDGES;
}

__global__ __launch_bounds__(256) void fill_kernel(
    const int* __restrict__ ei, int* __restrict__ cur, int* __restrict__ col)
{
    int e = blockIdx.x * 256 + threadIdx.x;
    if (e < N_EDGES) {
        int dst = ei[N_EDGES + e];
        int pos = atomicAdd(&cur[dst], 1);
        col[pos] = e;
    }
}

// ---------------------------------------------------------------------------
// Gather aggregation: 32 lanes per node, float4 per lane. Register accumulate.
// h[n] = (1+eps)*x[n] + sum_e relu(x[src_e] + emb[attr_e])  -> written to hbuf
// ---------------------------------------------------------------------------
__global__ __launch_bounds__(256) void gather_kernel(
    const float* __restrict__ x,
    const int* __restrict__ ei,
    const int* __restrict__ ea,
    const float* __restrict__ emb,
    const int* __restrict__ rs,
    const int* __restrict__ col,
    const float* __restrict__ eps_p,
    float* __restrict__ hbuf)
{
    int gid = blockIdx.x * 256 + threadIdx.x;
    int n = gid >> 5;
    if (n >= N_NODES) return;
    int c = gid & 31;

    int start = rs[n], end = rs[n + 1];
    float4 acc = make_float4(0.f, 0.f, 0.f, 0.f);
    for (int p = start; p < end; ++p) {
        int e   = col[p];
        int src = ei[e];
        int at  = ea[e];
        float4 xv = ((const float4*)(x   + (size_t)src * DIM))[c];
        float4 ev = ((const float4*)(emb + (size_t)at  * DIM))[c];
        acc.x += fmaxf(xv.x + ev.x, 0.f);
        acc.y += fmaxf(xv.y + ev.y, 0.f);
        acc.z += fmaxf(xv.z + ev.z, 0.f);
        acc.w += fmaxf(xv.w + ev.w, 0.f);
    }
    float epsv = 1.0f + eps_p[0];
    float4 xn = ((const float4*)(x + (size_t)n * DIM))[c];
    float4 o;
    o.x = epsv * xn.x + acc.x;
    o.y = epsv * xn.y + acc.y;
    o.z = epsv * xn.z + acc.z;
    o.w = epsv * xn.w + acc.w;
    ((float4*)(hbuf + (size_t)n * DIM))[c] = o;
}

// ---------------------------------------------------------------------------
// MLP1 in-place: h1 = relu(LN(h@W1 + b1)) over rows of hio
// ---------------------------------------------------------------------------
__global__ __launch_bounds__(256) void gine_mlp1(
    float* __restrict__ hio,
    const float* __restrict__ W1,
    const float* __restrict__ b1,
    const float* __restrict__ ln_g,
    const float* __restrict__ ln_b)
{
    __shared__ float w1s[DIM * DIM];
    __shared__ float hrow[8][DIM];

    for (int i = threadIdx.x; i < DIM * DIM / 4; i += 256)
        ((float4*)w1s)[i] = ((const float4*)W1)[i];

    const int n_local = threadIdx.x >> 5;
    const int lane32  = threadIdx.x & 31;
    const int jj = lane32 * 4;

    const float4 bv = *(const float4*)(b1 + jj);
    const float4 gv = *(const float4*)(ln_g + jj);
    const float4 bb = *(const float4*)(ln_b + jj);

    for (int base = blockIdx.x * 8; base < N_NODES; base += gridDim.x * 8) {
        __syncthreads();
        {
            int r = threadIdx.x >> 5, c = threadIdx.x & 31;
            int node = base + r;
            if (node < N_NODES)
                ((float4*)hrow[r])[c] = ((const float4*)(hio + (size_t)node * DIM))[c];
        }
        __syncthreads();

        int node = base + n_local;
        if (node >= N_NODES) continue;

        float4 acc = bv;
        #pragma unroll 8
        for (int k = 0; k < DIM; ++k) {
            float hv = hrow[n_local][k];
            float4 wv = *(const float4*)(w1s + k * DIM + jj);
            acc.x = fmaf(hv, wv.x, acc.x);
            acc.y = fmaf(hv, wv.y, acc.y);
            acc.z = fmaf(hv, wv.z, acc.z);
            acc.w = fmaf(hv, wv.w, acc.w);
        }

        float s1 = acc.x + acc.y + acc.z + acc.w;
        float s2 = acc.x * acc.x + acc.y * acc.y + acc.z * acc.z + acc.w * acc.w;
        #pragma unroll
        for (int m = 16; m; m >>= 1) {
            s1 += __shfl_xor(s1, m);
            s2 += __shfl_xor(s2, m);
        }
        float mu  = s1 * (1.0f / DIM);
        float var = s2 * (1.0f / DIM) - mu * mu;
        float rs_ = rsqrtf(var + 1e-5f);

        float4 o;
        o.x = fmaxf((acc.x - mu) * rs_ * gv.x + bb.x, 0.0f);
        o.y = fmaxf((acc.y - mu) * rs_ * gv.y + bb.y, 0.0f);
        o.z = fmaxf((acc.z - mu) * rs_ * gv.z + bb.z, 0.0f);
        o.w = fmaxf((acc.w - mu) * rs_ * gv.w + bb.w, 0.0f);
        *(float4*)(hio + (size_t)node * DIM + jj) = o;
    }
}

// ---------------------------------------------------------------------------
// MLP2 in-place: out = h1@W2 + b2 over rows of hio
// ---------------------------------------------------------------------------
__global__ __launch_bounds__(256) void gine_mlp2(
    float* __restrict__ hio,
    const float* __restrict__ W2,
    const float* __restrict__ b2)
{
    __shared__ float w2s[DIM * DIM];
    __shared__ float hrow[8][DIM];

    for (int i = threadIdx.x; i < DIM * DIM / 4; i += 256)
        ((float4*)w2s)[i] = ((const float4*)W2)[i];

    const int n_local = threadIdx.x >> 5;
    const int lane32  = threadIdx.x & 31;
    const int jj = lane32 * 4;
    const float4 bv = *(const float4*)(b2 + jj);

    for (int base = blockIdx.x * 8; base < N_NODES; base += gridDim.x * 8) {
        __syncthreads();
        {
            int r = threadIdx.x >> 5, c = threadIdx.x & 31;
            int node = base + r;
            if (node < N_NODES)
                ((float4*)hrow[r])[c] = ((const float4*)(hio + (size_t)node * DIM))[c];
        }
        __syncthreads();

        int node = base + n_local;
        if (node >= N_NODES) continue;

        float4 acc = bv;
        #pragma unroll 8
        for (int k = 0; k < DIM; ++k) {
            float hv = hrow[n_local][k];
            float4 wv = *(const float4*)(w2s + k * DIM + jj);
            acc.x = fmaf(hv, wv.x, acc.x);
            acc.y = fmaf(hv, wv.y, acc.y);
            acc.z = fmaf(hv, wv.z, acc.z);
            acc.w = fmaf(hv, wv.w, acc.w);
        }
        *(float4*)(hio + (size_t)node * DIM + jj) = acc;
    }
}

extern "C" void kernel_launch(void* const* d_in, const int* in_sizes, int n_in,
                              void* d_out, int out_size, void* d_ws, size_t ws_size,
                              hipStream_t stream) {
    const float* x    = (const float*)d_in[0];
    const int*   ei   = (const int*)d_in[1];
    const int*   ea   = (const int*)d_in[2];
    const float* emb  = (const float*)d_in[3];
    const float* epsp = (const float*)d_in[4];
    const float* W1   = (const float*)d_in[5];
    const float* b1   = (const float*)d_in[6];
    const float* lng  = (const float*)d_in[7];
    const float* lnb  = (const float*)d_in[8];
    const float* W2   = (const float*)d_in[9];
    const float* b2   = (const float*)d_in[10];
    float* out = (float*)d_out;

    // workspace layout (bytes)
    char* ws = (char*)d_ws;
    int* rs    = (int*)(ws);                 // (N_NODES+1) ints
    int* cur   = (int*)(ws + 401408);        // N_NODES ints (hist target, then cursor)
    int* bsums = (int*)(ws + 802816);        // NB ints
    int* col   = (int*)(ws + 803840);        // N_EDGES ints

    hipMemsetAsync(cur, 0, N_NODES * sizeof(int), stream);

    hist_kernel<<<(N_EDGES + 255) / 256, 256, 0, stream>>>(ei, cur);
    scan1_kernel<<<NB, 256, 0, stream>>>(cur, rs, bsums);
    scan2_kernel<<<1, 128, 0, stream>>>(bsums);
    scan3_kernel<<<(N_NODES + 255) / 256, 256, 0, stream>>>(rs, cur, bsums);
    fill_kernel<<<(N_EDGES + 255) / 256, 256, 0, stream>>>(ei, cur, col);

    gather_kernel<<<(N_NODES * 32 + 255) / 256, 256, 0, stream>>>(
        x, ei, ea, emb, rs, col, epsp, out);

    gine_mlp1<<<512, 256, 0, stream>>>(out, W1, b1, lng, lnb);
    gine_mlp2<<<512, 256, 0, stream>>>(out, W2, b2);
}

// Round 3
// 467.887 us; speedup vs baseline: 6.2099x; 1.2641x over previous
//
#include <hip/hip_runtime.h>

#define N_NODES 100000
#define N_EDGES 1600000
#define DIM 128
#define NB 98   // ceil(N_NODES / 1024)

// ---------------------------------------------------------------------------
// CSR build: histogram -> block scan -> scan of block sums -> add offsets -> fill
// ---------------------------------------------------------------------------
__global__ __launch_bounds__(256) void hist_kernel(
    const int* __restrict__ ei, int* __restrict__ cur)
{
    int e = blockIdx.x * 256 + threadIdx.x;
    if (e < N_EDGES) atomicAdd(&cur[ei[N_EDGES + e]], 1);
}

__global__ __launch_bounds__(256) void scan1_kernel(
    const int* __restrict__ deg, int* __restrict__ rs, int* __restrict__ bsums)
{
    __shared__ int s[256];
    int t = threadIdx.x;
    int base = blockIdx.x * 1024 + t * 4;
    int v0 = (base + 0 < N_NODES) ? deg[base + 0] : 0;
    int v1 = (base + 1 < N_NODES) ? deg[base + 1] : 0;
    int v2 = (base + 2 < N_NODES) ? deg[base + 2] : 0;
    int v3 = (base + 3 < N_NODES) ? deg[base + 3] : 0;
    int sum = v0 + v1 + v2 + v3;
    s[t] = sum;
    __syncthreads();
    for (int off = 1; off < 256; off <<= 1) {
        int x = (t >= off) ? s[t - off] : 0;
        __syncthreads();
        s[t] += x;
        __syncthreads();
    }
    int excl = s[t] - sum;
    if (base + 0 < N_NODES) rs[base + 0] = excl;  excl += v0;
    if (base + 1 < N_NODES) rs[base + 1] = excl;  excl += v1;
    if (base + 2 < N_NODES) rs[base + 2] = excl;  excl += v2;
    if (base + 3 < N_NODES) rs[base + 3] = excl;
    if (t == 255) bsums[blockIdx.x] = s[255];
}

__global__ __launch_bounds__(128) void scan2_kernel(int* __restrict__ bsums)
{
    __shared__ int s[128];
    int t = threadIdx.x;
    int v = (t < NB) ? bsums[t] : 0;
    s[t] = v;
    __syncthreads();
    for (int off = 1; off < 128; off <<= 1) {
        int x = (t >= off) ? s[t - off] : 0;
        __syncthreads();
        s[t] += x;
        __syncthreads();
    }
    if (t < NB) bsums[t] = s[t] - v;   // exclusive
}

__global__ __launch_bounds__(256) void scan3_kernel(
    int* __restrict__ rs, int* __restrict__ cur, const int* __restrict__ bsums)
{
    int i = blockIdx.x * 256 + threadIdx.x;
    if (i < N_NODES) {
        int v = rs[i] + bsums[i >> 10];
        rs[i] = v;
        cur[i] = v;
    }
    if (i == 0) rs[N_NODES] = N_EDGES;
}

// fill: pack (src, attr) into one int: src | (attr<<17). src < 2^17, attr < 4.
__global__ __launch_bounds__(256) void fill_kernel(
    const int* __restrict__ ei, const int* __restrict__ ea,
    int* __restrict__ cur, int* __restrict__ col)
{
    int e = blockIdx.x * 256 + threadIdx.x;
    if (e < N_EDGES) {
        int dst = ei[N_EDGES + e];
        int src = ei[e];
        int at  = ea[e];
        int pos = atomicAdd(&cur[dst], 1);
        col[pos] = src | (at << 17);
    }
}

// ---------------------------------------------------------------------------
// Gather aggregation: 32 lanes per node, float4 per lane, x4 unrolled edges.
// h[n] = (1+eps)*x[n] + sum_e relu(x[src_e] + emb[attr_e])  -> hbuf
// ---------------------------------------------------------------------------
__global__ __launch_bounds__(256) void gather_kernel(
    const float* __restrict__ x,
    const float* __restrict__ emb,
    const int* __restrict__ rs,
    const int* __restrict__ col,
    const float* __restrict__ eps_p,
    float* __restrict__ hbuf)
{
    int gid = blockIdx.x * 256 + threadIdx.x;
    int n = gid >> 5;
    if (n >= N_NODES) return;
    int c = gid & 31;

    int start = rs[n], end = rs[n + 1];
    float4 acc = make_float4(0.f, 0.f, 0.f, 0.f);

    int p = start;
    for (; p + 4 <= end; p += 4) {
        int pk0 = col[p + 0];
        int pk1 = col[p + 1];
        int pk2 = col[p + 2];
        int pk3 = col[p + 3];
        float4 x0 = ((const float4*)(x + (size_t)(pk0 & 0x1FFFF) * DIM))[c];
        float4 x1 = ((const float4*)(x + (size_t)(pk1 & 0x1FFFF) * DIM))[c];
        float4 x2 = ((const float4*)(x + (size_t)(pk2 & 0x1FFFF) * DIM))[c];
        float4 x3 = ((const float4*)(x + (size_t)(pk3 & 0x1FFFF) * DIM))[c];
        float4 e0 = ((const float4*)(emb + (size_t)((unsigned)pk0 >> 17) * DIM))[c];
        float4 e1 = ((const float4*)(emb + (size_t)((unsigned)pk1 >> 17) * DIM))[c];
        float4 e2 = ((const float4*)(emb + (size_t)((unsigned)pk2 >> 17) * DIM))[c];
        float4 e3 = ((const float4*)(emb + (size_t)((unsigned)pk3 >> 17) * DIM))[c];
        acc.x += fmaxf(x0.x + e0.x, 0.f) + fmaxf(x1.x + e1.x, 0.f)
               + fmaxf(x2.x + e2.x, 0.f) + fmaxf(x3.x + e3.x, 0.f);
        acc.y += fmaxf(x0.y + e0.y, 0.f) + fmaxf(x1.y + e1.y, 0.f)
               + fmaxf(x2.y + e2.y, 0.f) + fmaxf(x3.y + e3.y, 0.f);
        acc.z += fmaxf(x0.z + e0.z, 0.f) + fmaxf(x1.z + e1.z, 0.f)
               + fmaxf(x2.z + e2.z, 0.f) + fmaxf(x3.z + e3.z, 0.f);
        acc.w += fmaxf(x0.w + e0.w, 0.f) + fmaxf(x1.w + e1.w, 0.f)
               + fmaxf(x2.w + e2.w, 0.f) + fmaxf(x3.w + e3.w, 0.f);
    }
    for (; p < end; ++p) {
        int pk = col[p];
        float4 xv = ((const float4*)(x + (size_t)(pk & 0x1FFFF) * DIM))[c];
        float4 ev = ((const float4*)(emb + (size_t)((unsigned)pk >> 17) * DIM))[c];
        acc.x += fmaxf(xv.x + ev.x, 0.f);
        acc.y += fmaxf(xv.y + ev.y, 0.f);
        acc.z += fmaxf(xv.z + ev.z, 0.f);
        acc.w += fmaxf(xv.w + ev.w, 0.f);
    }

    float epsv = 1.0f + eps_p[0];
    float4 xn = ((const float4*)(x + (size_t)n * DIM))[c];
    float4 o;
    o.x = epsv * xn.x + acc.x;
    o.y = epsv * xn.y + acc.y;
    o.z = epsv * xn.z + acc.z;
    o.w = epsv * xn.w + acc.w;
    ((float4*)(hbuf + (size_t)n * DIM))[c] = o;
}

// ---------------------------------------------------------------------------
// MLP1 in-place: h1 = relu(LN(h@W1 + b1)). 32-node tile, thread = 4 nodes x 4 cols.
// ---------------------------------------------------------------------------
__global__ __launch_bounds__(256) void gine_mlp1(
    float* __restrict__ hio,
    const float* __restrict__ W1,
    const float* __restrict__ b1,
    const float* __restrict__ ln_g,
    const float* __restrict__ ln_b)
{
    __shared__ float w1s[DIM * DIM];   // 64KB
    __shared__ float hrow[32][DIM];    // 16KB

    for (int i = threadIdx.x; i < DIM * DIM / 4; i += 256)
        ((float4*)w1s)[i] = ((const float4*)W1)[i];

    const int tx = threadIdx.x & 31;
    const int ty = threadIdx.x >> 5;   // 0..7
    const int jj = tx * 4;
    const int base = blockIdx.x * 32;

    for (int i = threadIdx.x; i < 1024; i += 256) {
        int r = i >> 5, cc = i & 31;
        ((float4*)hrow[r])[cc] = ((const float4*)(hio + (size_t)(base + r) * DIM))[cc];
    }
    __syncthreads();

    const float4 bv = *(const float4*)(b1 + jj);
    const float4 gv = *(const float4*)(ln_g + jj);
    const float4 bb = *(const float4*)(ln_b + jj);

    float4 a0 = bv, a1 = bv, a2 = bv, a3 = bv;
    #pragma unroll 4
    for (int k = 0; k < DIM; ++k) {
        float4 wv = *(const float4*)(w1s + k * DIM + jj);
        float h0 = hrow[ty +  0][k];
        float h1 = hrow[ty +  8][k];
        float h2 = hrow[ty + 16][k];
        float h3 = hrow[ty + 24][k];
        a0.x = fmaf(h0, wv.x, a0.x); a0.y = fmaf(h0, wv.y, a0.y);
        a0.z = fmaf(h0, wv.z, a0.z); a0.w = fmaf(h0, wv.w, a0.w);
        a1.x = fmaf(h1, wv.x, a1.x); a1.y = fmaf(h1, wv.y, a1.y);
        a1.z = fmaf(h1, wv.z, a1.z); a1.w = fmaf(h1, wv.w, a1.w);
        a2.x = fmaf(h2, wv.x, a2.x); a2.y = fmaf(h2, wv.y, a2.y);
        a2.z = fmaf(h2, wv.z, a2.z); a2.w = fmaf(h2, wv.w, a2.w);
        a3.x = fmaf(h3, wv.x, a3.x); a3.y = fmaf(h3, wv.y, a3.y);
        a3.z = fmaf(h3, wv.z, a3.z); a3.w = fmaf(h3, wv.w, a3.w);
    }

    #pragma unroll
    for (int q = 0; q < 4; ++q) {
        float4 acc = (q == 0) ? a0 : (q == 1) ? a1 : (q == 2) ? a2 : a3;
        float s1 = acc.x + acc.y + acc.z + acc.w;
        float s2 = acc.x * acc.x + acc.y * acc.y + acc.z * acc.z + acc.w * acc.w;
        #pragma unroll
        for (int m = 16; m; m >>= 1) {
            s1 += __shfl_xor(s1, m);
            s2 += __shfl_xor(s2, m);
        }
        float mu  = s1 * (1.0f / DIM);
        float var = s2 * (1.0f / DIM) - mu * mu;
        float rs_ = rsqrtf(var + 1e-5f);
        float4 o;
        o.x = fmaxf((acc.x - mu) * rs_ * gv.x + bb.x, 0.0f);
        o.y = fmaxf((acc.y - mu) * rs_ * gv.y + bb.y, 0.0f);
        o.z = fmaxf((acc.z - mu) * rs_ * gv.z + bb.z, 0.0f);
        o.w = fmaxf((acc.w - mu) * rs_ * gv.w + bb.w, 0.0f);
        *(float4*)(hio + (size_t)(base + ty + 8 * q) * DIM + jj) = o;
    }
}

// ---------------------------------------------------------------------------
// MLP2: out = h1@W2 + b2, same tiling, reads hio writes out.
// ---------------------------------------------------------------------------
__global__ __launch_bounds__(256) void gine_mlp2(
    const float* __restrict__ hio,
    const float* __restrict__ W2,
    const float* __restrict__ b2,
    float* __restrict__ out)
{
    __shared__ float w2s[DIM * DIM];
    __shared__ float hrow[32][DIM];

    for (int i = threadIdx.x; i < DIM * DIM / 4; i += 256)
        ((float4*)w2s)[i] = ((const float4*)W2)[i];

    const int tx = threadIdx.x & 31;
    const int ty = threadIdx.x >> 5;
    const int jj = tx * 4;
    const int base = blockIdx.x * 32;

    for (int i = threadIdx.x; i < 1024; i += 256) {
        int r = i >> 5, cc = i & 31;
        ((float4*)hrow[r])[cc] = ((const float4*)(hio + (size_t)(base + r) * DIM))[cc];
    }
    __syncthreads();

    const float4 bv = *(const float4*)(b2 + jj);
    float4 a0 = bv, a1 = bv, a2 = bv, a3 = bv;
    #pragma unroll 4
    for (int k = 0; k < DIM; ++k) {
        float4 wv = *(const float4*)(w2s + k * DIM + jj);
        float h0 = hrow[ty +  0][k];
        float h1 = hrow[ty +  8][k];
        float h2 = hrow[ty + 16][k];
        float h3 = hrow[ty + 24][k];
        a0.x = fmaf(h0, wv.x, a0.x); a0.y = fmaf(h0, wv.y, a0.y);
        a0.z = fmaf(h0, wv.z, a0.z); a0.w = fmaf(h0, wv.w, a0.w);
        a1.x = fmaf(h1, wv.x, a1.x); a1.y = fmaf(h1, wv.y, a1.y);
        a1.z = fmaf(h1, wv.z, a1.z); a1.w = fmaf(h1, wv.w, a1.w);
        a2.x = fmaf(h2, wv.x, a2.x); a2.y = fmaf(h2, wv.y, a2.y);
        a2.z = fmaf(h2, wv.z, a2.z); a2.w = fmaf(h2, wv.w, a2.w);
        a3.x = fmaf(h3, wv.x, a3.x); a3.y = fmaf(h3, wv.y, a3.y);
        a3.z = fmaf(h3, wv.z, a3.z); a3.w = fmaf(h3, wv.w, a3.w);
    }

    *(float4*)(out + (size_t)(base + ty +  0) * DIM + jj) = a0;
    *(float4*)(out + (size_t)(base + ty +  8) * DIM + jj) = a1;
    *(float4*)(out + (size_t)(base + ty + 16) * DIM + jj) = a2;
    *(float4*)(out + (size_t)(base + ty + 24) * DIM + jj) = a3;
}

extern "C" void kernel_launch(void* const* d_in, const int* in_sizes, int n_in,
                              void* d_out, int out_size, void* d_ws, size_t ws_size,
                              hipStream_t stream) {
    const float* x    = (const float*)d_in[0];
    const int*   ei   = (const int*)d_in[1];
    const int*   ea   = (const int*)d_in[2];
    const float* emb  = (const float*)d_in[3];
    const float* epsp = (const float*)d_in[4];
    const float* W1   = (const float*)d_in[5];
    const float* b1   = (const float*)d_in[6];
    const float* lng  = (const float*)d_in[7];
    const float* lnb  = (const float*)d_in[8];
    const float* W2   = (const float*)d_in[9];
    const float* b2   = (const float*)d_in[10];
    float* out = (float*)d_out;

    // workspace layout (bytes)
    char* ws = (char*)d_ws;
    int* rs    = (int*)(ws);                 // (N_NODES+1) ints
    int* cur   = (int*)(ws + 401408);        // N_NODES ints (hist, then cursor)
    int* bsums = (int*)(ws + 802816);        // NB ints
    int* col   = (int*)(ws + 803840);        // N_EDGES ints (packed src|at<<17)
    float* hbuf = (float*)(ws + 803840 + (size_t)N_EDGES * 4);  // [N,128]

    hipMemsetAsync(cur, 0, N_NODES * sizeof(int), stream);

    hist_kernel<<<(N_EDGES + 255) / 256, 256, 0, stream>>>(ei, cur);
    scan1_kernel<<<NB, 256, 0, stream>>>(cur, rs, bsums);
    scan2_kernel<<<1, 128, 0, stream>>>(bsums);
    scan3_kernel<<<(N_NODES + 255) / 256, 256, 0, stream>>>(rs, cur, bsums);
    fill_kernel<<<(N_EDGES + 255) / 256, 256, 0, stream>>>(ei, ea, cur, col);

    gather_kernel<<<(N_NODES * 32) / 256, 256, 0, stream>>>(
        x, emb, rs, col, epsp, hbuf);

    gine_mlp1<<<N_NODES / 32, 256, 0, stream>>>(hbuf, W1, b1, lng, lnb);
    gine_mlp2<<<N_NODES / 32, 256, 0, stream>>>(hbuf, W2, b2, out);
}